// Round 2
// baseline (65.883 us; speedup 1.0000x reference)
//
#include <hip/hip_runtime.h>

constexpr int SEQ_LEN = 200;
constexpr int BATCH   = 4096;
constexpr int V       = 50000;

constexpr int DOCS    = 16;               // docs per block
constexpr int NTHR    = 512;
constexpr int SLICES  = NTHR / DOCS;      // 32 t-slices
constexpr int TOK_PT  = (SEQ_LEN + SLICES - 1) / SLICES;  // 7 tokens max per thread
constexpr int HSLOTS  = 512;              // hash slots per doc (>= 200 uniques, pow2)
constexpr unsigned EMPTY = 0xFFFFFFFFu;

__global__ __launch_bounds__(NTHR) void MNB_8151847928093_kernel(
    const int*   __restrict__ text,   // [SEQ_LEN, BATCH]
    const float* __restrict__ W,      // [V]
    const float* __restrict__ bias,   // [1]
    float*       __restrict__ out)    // [BATCH]
{
    // interleaved per-doc hash sets: slot s of doc d at ht[s*DOCS + d]
    __shared__ unsigned ht[HSLOTS * DOCS];          // 32 KB
    __shared__ float    psum[SLICES * DOCS];        // 2 KB

    const int tid   = threadIdx.x;
    const int doc   = tid & (DOCS - 1);
    const int slice = tid >> 4;                     // 0..31
    const int b     = blockIdx.x * DOCS + doc;

    for (int i = tid; i < HSLOTS * DOCS; i += NTHR) ht[i] = EMPTY;
    __syncthreads();

    // stage this thread's tokens in registers (independent coalesced loads)
    unsigned toks[TOK_PT];
    #pragma unroll
    for (int i = 0; i < TOK_PT; ++i) {
        const int t = slice + i * SLICES;
        toks[i] = (t < SEQ_LEN) ? (unsigned)text[t * BATCH + b] : EMPTY;
    }

    // dedup-insert; first setter of a token accumulates W[tok]
    float sum = 0.0f;
    #pragma unroll
    for (int i = 0; i < TOK_PT; ++i) {
        const unsigned tok = toks[i];
        if (tok == EMPTY) continue;
        unsigned slot = ((tok * 2654435761u) >> 16) & (HSLOTS - 1);
        while (true) {
            const unsigned old = atomicCAS(&ht[slot * DOCS + doc], EMPTY, tok);
            if (old == EMPTY) { sum += W[tok]; break; }   // newly inserted
            if (old == tok)   { break; }                  // duplicate
            slot = (slot + 1) & (HSLOTS - 1);             // probe
        }
    }

    psum[slice * DOCS + doc] = sum;
    __syncthreads();

    if (tid < DOCS) {
        float s = bias[0];
        #pragma unroll
        for (int k = 0; k < SLICES; ++k) s += psum[k * DOCS + tid];
        out[blockIdx.x * DOCS + tid] = s;
    }
}

extern "C" void kernel_launch(void* const* d_in, const int* in_sizes, int n_in,
                              void* d_out, int out_size, void* d_ws, size_t ws_size,
                              hipStream_t stream) {
    const int*   text = (const int*)d_in[0];
    const float* W    = (const float*)d_in[1];
    const float* bias = (const float*)d_in[2];
    float*       out  = (float*)d_out;

    MNB_8151847928093_kernel<<<BATCH / DOCS, NTHR, 0, stream>>>(text, W, bias, out);
}

// Round 3
// 63.954 us; speedup vs baseline: 1.0302x; 1.0302x over previous
//
#include <hip/hip_runtime.h>

constexpr int SEQ_LEN = 200;
constexpr int BATCH   = 4096;
constexpr int V       = 50000;

constexpr int DOCS    = 16;               // docs per block
constexpr int NTHR    = 1024;             // 16 waves/CU
constexpr int SLICES  = NTHR / DOCS;      // 64 t-slices per doc
constexpr int TOK_PT  = (SEQ_LEN + SLICES - 1) / SLICES;  // 4 tokens per thread
constexpr int HSLOTS  = 512;              // hash slots per doc (pow2, load 0.39)
constexpr unsigned EMPTY = 0xFFFFFFFFu;

__global__ __launch_bounds__(NTHR) void MNB_8151847928093_kernel(
    const int*   __restrict__ text,   // [SEQ_LEN, BATCH]
    const float* __restrict__ W,      // [V]
    const float* __restrict__ bias,   // [1]
    float*       __restrict__ out)    // [BATCH]
{
    // interleaved per-doc hash sets: slot s of doc d at ht[s*DOCS + d]
    __shared__ unsigned ht[HSLOTS * DOCS];              // 32 KB
    __shared__ float    psum[(NTHR / 64) * DOCS];       // 16 waves x 16 docs

    const int tid   = threadIdx.x;
    const int doc   = tid & (DOCS - 1);
    const int slice = tid >> 4;                         // 0..63
    const int b     = blockIdx.x * DOCS + doc;

    for (int i = tid; i < HSLOTS * DOCS; i += NTHR) ht[i] = EMPTY;
    __syncthreads();

    // 1) stage tokens (independent coalesced loads, all in flight)
    unsigned toks[TOK_PT];
    #pragma unroll
    for (int i = 0; i < TOK_PT; ++i) {
        const int t = slice + i * SLICES;
        toks[i] = (t < SEQ_LEN) ? (unsigned)text[t * BATCH + b] : EMPTY;
    }

    // 2) speculatively prefetch W[tok] (independent of CAS results)
    float wv[TOK_PT];
    #pragma unroll
    for (int i = 0; i < TOK_PT; ++i)
        wv[i] = W[toks[i] == EMPTY ? 0u : toks[i]];

    // 3) first-probe CASes, issued back-to-back (independent addresses)
    unsigned hs[TOK_PT], od[TOK_PT];
    #pragma unroll
    for (int i = 0; i < TOK_PT; ++i) {
        hs[i] = ((toks[i] * 2654435761u) >> 16) & (HSLOTS - 1);
        od[i] = (toks[i] != EMPTY)
                    ? atomicCAS(&ht[hs[i] * DOCS + doc], EMPTY, toks[i])
                    : 0u;
    }

    // 4) resolve: first inserter owns the token; collisions probe (rare)
    float sum = 0.0f;
    #pragma unroll
    for (int i = 0; i < TOK_PT; ++i) {
        const unsigned tok = toks[i];
        if (tok == EMPTY) continue;
        const unsigned old = od[i];
        if (old == EMPTY) { sum += wv[i]; }
        else if (old != tok) {
            unsigned slot = (hs[i] + 1) & (HSLOTS - 1);
            while (true) {
                const unsigned o = atomicCAS(&ht[slot * DOCS + doc], EMPTY, tok);
                if (o == EMPTY) { sum += wv[i]; break; }
                if (o == tok)   { break; }
                slot = (slot + 1) & (HSLOTS - 1);
            }
        }
    }

    // 5) reduce 64 slices/doc: lanes {l, l+16, l+32, l+48} share a doc
    sum += __shfl_down(sum, 32, 64);
    sum += __shfl_down(sum, 16, 64);
    const int wave = tid >> 6;
    const int lane = tid & 63;
    if (lane < DOCS) psum[wave * DOCS + lane] = sum;
    __syncthreads();

    if (tid < DOCS) {
        float s = bias[0];
        #pragma unroll
        for (int k = 0; k < NTHR / 64; ++k) s += psum[k * DOCS + tid];
        out[blockIdx.x * DOCS + tid] = s;
    }
}

extern "C" void kernel_launch(void* const* d_in, const int* in_sizes, int n_in,
                              void* d_out, int out_size, void* d_ws, size_t ws_size,
                              hipStream_t stream) {
    const int*   text = (const int*)d_in[0];
    const float* W    = (const float*)d_in[1];
    const float* bias = (const float*)d_in[2];
    float*       out  = (float*)d_out;

    MNB_8151847928093_kernel<<<BATCH / DOCS, NTHR, 0, stream>>>(text, W, bias, out);
}